// Round 1
// baseline (331.697 us; speedup 1.0000x reference)
//
#include <hip/hip_runtime.h>

#define NB 4
#define NH 12
#define DHD 64
#define LQ 512
#define LK 512
#define DM 768

// ---------------------------------------------------------------------------
// Kernel 0: LayerNorm of the 3x64 relation embedding tables (k and v).
// ---------------------------------------------------------------------------
__global__ __launch_bounds__(64) void prep_ln_kernel(
    const float* __restrict__ dpk, const float* __restrict__ dpv,
    const float* __restrict__ gk, const float* __restrict__ bk,
    const float* __restrict__ gv, const float* __restrict__ bv,
    float* __restrict__ lnK, float* __restrict__ lnV)
{
    int lane = threadIdx.x;  // 64 threads = 1 wave
    for (int r = 0; r < 3; ++r) {
        {
            float x = dpk[r * DHD + lane];
            float s = x;
            #pragma unroll
            for (int o = 1; o < 64; o <<= 1) s += __shfl_xor(s, o);
            float mu = s * (1.0f / 64.0f);
            float d = x - mu;
            float v = d * d;
            #pragma unroll
            for (int o = 1; o < 64; o <<= 1) v += __shfl_xor(v, o);
            float var = v * (1.0f / 64.0f);
            lnK[r * DHD + lane] = d * rsqrtf(var + 1e-5f) * gk[lane] + bk[lane];
        }
        {
            float x = dpv[r * DHD + lane];
            float s = x;
            #pragma unroll
            for (int o = 1; o < 64; o <<= 1) s += __shfl_xor(s, o);
            float mu = s * (1.0f / 64.0f);
            float d = x - mu;
            float v = d * d;
            #pragma unroll
            for (int o = 1; o < 64; o <<= 1) v += __shfl_xor(v, o);
            float var = v * (1.0f / 64.0f);
            lnV[r * DHD + lane] = d * rsqrtf(var + 1e-5f) * gv[lane] + bv[lane];
        }
    }
}

// ---------------------------------------------------------------------------
// Kernel 1: fused QKV projection. C[m, n] = X[m, :] @ W[:, n] + bias[n].
// grid.x = 32 M-tiles (64 rows), grid.y = 36 N-tiles (64 cols; 12 per matrix).
// Output written directly in [B, H, L, DH] layout to workspace.
// 64x64 tile, 256 threads, 4x4 register micro-tile, K-tile = 32.
// ---------------------------------------------------------------------------
__global__ __launch_bounds__(256) void qkv_kernel(
    const float* __restrict__ hidden, const float* __restrict__ context,
    const float* __restrict__ Wq, const float* __restrict__ bq,
    const float* __restrict__ Wk, const float* __restrict__ bk,
    const float* __restrict__ Wv, const float* __restrict__ bv,
    float* __restrict__ Qw, float* __restrict__ Kw, float* __restrict__ Vw)
{
    __shared__ float sXT[32][68];   // X tile transposed: [k][m]
    __shared__ float sW[32][64];    // W tile: [k][n]

    int t = threadIdx.x;
    int bxm = blockIdx.x;          // 0..31
    int byn = blockIdx.y;          // 0..35
    int mat = byn / 12;            // 0=Q, 1=K, 2=V
    int hcol = byn % 12;           // head index
    const float* X   = (mat == 0) ? hidden : context;
    const float* W   = (mat == 0) ? Wq : (mat == 1) ? Wk : Wv;
    const float* bias= (mat == 0) ? bq : (mat == 1) ? bk : bv;
    float* dst       = (mat == 0) ? Qw : (mat == 1) ? Kw : Vw;

    int m0 = bxm * 64;
    int n0 = hcol * 64;
    int ty = t >> 4, tx = t & 15;

    float c[4][4];
    #pragma unroll
    for (int i = 0; i < 4; ++i)
        #pragma unroll
        for (int j = 0; j < 4; ++j) c[i][j] = 0.0f;

    for (int kt = 0; kt < 24; ++kt) {
        __syncthreads();
        // stage X tile (64 rows x 32 k), transposed into sXT[k][m]
        #pragma unroll
        for (int p = 0; p < 2; ++p) {
            int idx = t + p * 256;
            int ml = idx >> 3, kq = idx & 7;
            float4 xv = *(const float4*)&X[(m0 + ml) * DM + kt * 32 + kq * 4];
            sXT[kq * 4 + 0][ml] = xv.x;
            sXT[kq * 4 + 1][ml] = xv.y;
            sXT[kq * 4 + 2][ml] = xv.z;
            sXT[kq * 4 + 3][ml] = xv.w;
        }
        // stage W tile (32 k x 64 n)
        #pragma unroll
        for (int p = 0; p < 2; ++p) {
            int idx = t + p * 256;
            int kl = idx >> 4, nq = idx & 15;
            *(float4*)&sW[kl][nq * 4] =
                *(const float4*)&W[(kt * 32 + kl) * DM + n0 + nq * 4];
        }
        __syncthreads();
        #pragma unroll 8
        for (int kk = 0; kk < 32; ++kk) {
            float4 a = *(const float4*)&sXT[kk][ty * 4];
            float4 b = *(const float4*)&sW[kk][tx * 4];
            float av[4] = {a.x, a.y, a.z, a.w};
            float bv4[4] = {b.x, b.y, b.z, b.w};
            #pragma unroll
            for (int i = 0; i < 4; ++i)
                #pragma unroll
                for (int j = 0; j < 4; ++j) c[i][j] += av[i] * bv4[j];
        }
    }

    float4 bb = *(const float4*)&bias[n0 + tx * 4];
    int bbatch = m0 >> 9;          // whole tile in one batch (64 | 512)
    #pragma unroll
    for (int i = 0; i < 4; ++i) {
        int m = m0 + ty * 4 + i;
        int l = m & 511;
        float4 o;
        o.x = c[i][0] + bb.x; o.y = c[i][1] + bb.y;
        o.z = c[i][2] + bb.z; o.w = c[i][3] + bb.w;
        *(float4*)&dst[((bbatch * NH + hcol) * LQ + l) * DHD + tx * 4] = o;
    }
}

// ---------------------------------------------------------------------------
// Kernel 2: attention. One block = (b, h, 16-query tile). 256 threads.
// Scores materialized transposed in LDS [k][q]; softmax with arc bucket-sums;
// PV + rank-3 lnV correction, scaled by 1/denom at the end.
// LDS total = 64,832 B.
// ---------------------------------------------------------------------------
__global__ __launch_bounds__(256) void attn_kernel(
    const float* __restrict__ Qw, const float* __restrict__ Kw,
    const float* __restrict__ Vw, const float* __restrict__ maskp,
    const int* __restrict__ garc,
    const float* __restrict__ lnK, const float* __restrict__ lnV,
    float* __restrict__ outp)
{
    __shared__ float sST[512][20];   // scores transposed: [k][q], 16 q + pad
    __shared__ float sKV[64][68];    // K tile [k][d] (scores) / V tile [k][d] (PV)
    __shared__ float sQ[16][68];     // Q tile [q][d]
    __shared__ float sLnK[3][64];
    __shared__ float sLnV[3][64];
    __shared__ float sTb[16][4];     // per-query dot with lnK rows
    __shared__ float sWr[16][4];     // per-query raw arc bucket sums
    __shared__ float sInv[16];       // 1/denom per query

    int t = threadIdx.x;
    int bx = blockIdx.x;
    int qt = bx & 31;              // 32 q-tiles of 16
    int h = (bx >> 5) % 12;
    int b = bx / 384;
    int q0 = qt * 16;

    const float* Qbase = Qw + ((size_t)(b * NH + h) * LQ) * DHD;
    const float* Kbase = Kw + ((size_t)(b * NH + h) * LK) * DHD;
    const float* Vbase = Vw + ((size_t)(b * NH + h) * LK) * DHD;

    // phase 0: load Q tile + LN tables
    {
        int ql = t >> 4, dq = t & 15;
        *(float4*)&sQ[ql][dq * 4] =
            *(const float4*)&Qbase[(q0 + ql) * DHD + dq * 4];
    }
    if (t < 192) {
        int r = t / 64, d = t & 63;
        sLnK[r][d] = lnK[r * 64 + d];
        sLnV[r][d] = lnV[r * 64 + d];
    }
    __syncthreads();

    // phase 1: tb[q][r] = q . lnK[r]
    if (t < 48) {
        int q = t / 3, r = t % 3;
        float acc = 0.0f;
        for (int d = 0; d < 64; ++d) acc += sQ[q][d] * sLnK[r][d];
        sTb[q][r] = acc;
    }

    int qg = t >> 4;       // 0..7 for t<128: q pair = {2qg, 2qg+1}
    int s  = t & 15;       // 0..15
    int tq = qg * 2;
    int s4 = s * 4;

    // phase 2: scores
    for (int kt = 0; kt < 8; ++kt) {
        __syncthreads();
        #pragma unroll
        for (int p = 0; p < 4; ++p) {
            int idx = t + p * 256;
            int kl = idx >> 4, dq = idx & 15;
            *(float4*)&sKV[kl][dq * 4] =
                *(const float4*)&Kbase[(kt * 64 + kl) * DHD + dq * 4];
        }
        __syncthreads();
        if (t < 128) {
            float a0[4] = {0, 0, 0, 0}, a1[4] = {0, 0, 0, 0};
            #pragma unroll 4
            for (int dc = 0; dc < 64; dc += 4) {
                float4 qA = *(const float4*)&sQ[tq][dc];
                float4 qB = *(const float4*)&sQ[tq + 1][dc];
                #pragma unroll
                for (int j = 0; j < 4; ++j) {
                    float4 kv = *(const float4*)&sKV[s + 16 * j][dc];
                    a0[j] += qA.x * kv.x + qA.y * kv.y + qA.z * kv.z + qA.w * kv.w;
                    a1[j] += qB.x * kv.x + qB.y * kv.y + qB.z * kv.z + qB.w * kv.w;
                }
            }
            int kg0 = kt * 64 + s;
            float mv[4];
            #pragma unroll
            for (int j = 0; j < 4; ++j) mv[j] = maskp[b * LK + kg0 + 16 * j];
            #pragma unroll
            for (int i = 0; i < 2; ++i) {
                int qgl = q0 + tq + i;
                const int* arow = &garc[((size_t)(b * LQ + qgl)) * LK];
                float* acc = i ? a1 : a0;
                #pragma unroll
                for (int j = 0; j < 4; ++j) {
                    int a = arow[kg0 + 16 * j];
                    sST[kg0 + 16 * j][tq + i] =
                        acc[j] * 0.125f + sTb[tq + i][a] + mv[j];
                }
            }
        }
    }
    __syncthreads();

    // phase 3: softmax per query row + arc bucket sums (unnormalized)
    {
        int q = t >> 4;       // 0..15
        int ss = t & 15;      // 16 lanes per row
        float m = -1e30f;
        for (int i = 0; i < 32; ++i) m = fmaxf(m, sST[ss + 16 * i][q]);
        #pragma unroll
        for (int o = 1; o < 16; o <<= 1) m = fmaxf(m, __shfl_xor(m, o));
        float sum = 0, w0 = 0, w1 = 0, w2 = 0;
        const int* arow = &garc[((size_t)(b * LQ + q0 + q)) * LK];
        for (int i = 0; i < 32; ++i) {
            int k = ss + 16 * i;
            float e = __expf(sST[k][q] - m);
            sST[k][q] = e;
            int a = arow[k];
            if (a == 0) w0 += e; else if (a == 1) w1 += e; else w2 += e;
            sum += e;
        }
        #pragma unroll
        for (int o = 1; o < 16; o <<= 1) {
            sum += __shfl_xor(sum, o);
            w0 += __shfl_xor(w0, o);
            w1 += __shfl_xor(w1, o);
            w2 += __shfl_xor(w2, o);
        }
        if (ss == 0) {
            sInv[q] = 1.0f / sum;
            sWr[q][0] = w0; sWr[q][1] = w1; sWr[q][2] = w2;
        }
    }

    // phase 4: PV
    float c0[4] = {0, 0, 0, 0}, c1[4] = {0, 0, 0, 0};
    for (int kt = 0; kt < 8; ++kt) {
        __syncthreads();
        #pragma unroll
        for (int p = 0; p < 4; ++p) {
            int idx = t + p * 256;
            int kl = idx >> 4, dq = idx & 15;
            *(float4*)&sKV[kl][dq * 4] =
                *(const float4*)&Vbase[(kt * 64 + kl) * DHD + dq * 4];
        }
        __syncthreads();
        if (t < 128) {
            #pragma unroll 8
            for (int kl = 0; kl < 64; ++kl) {
                float2 p2 = *(const float2*)&sST[kt * 64 + kl][tq];
                float4 vv = *(const float4*)&sKV[kl][s4];
                c0[0] += p2.x * vv.x; c0[1] += p2.x * vv.y;
                c0[2] += p2.x * vv.z; c0[3] += p2.x * vv.w;
                c1[0] += p2.y * vv.x; c1[1] += p2.y * vv.y;
                c1[2] += p2.y * vv.z; c1[3] += p2.y * vv.w;
            }
        }
    }

    // epilogue: add rank-3 lnV correction, normalize, store [B, Lq, H*DH]
    if (t < 128) {
        #pragma unroll
        for (int i = 0; i < 2; ++i) {
            int q = tq + i;
            float inv = sInv[q];
            float w0 = sWr[q][0], w1 = sWr[q][1], w2 = sWr[q][2];
            float* acc = i ? c1 : c0;
            float4 o;
            o.x = (acc[0] + w0 * sLnV[0][s4 + 0] + w1 * sLnV[1][s4 + 0] + w2 * sLnV[2][s4 + 0]) * inv;
            o.y = (acc[1] + w0 * sLnV[0][s4 + 1] + w1 * sLnV[1][s4 + 1] + w2 * sLnV[2][s4 + 1]) * inv;
            o.z = (acc[2] + w0 * sLnV[0][s4 + 2] + w1 * sLnV[1][s4 + 2] + w2 * sLnV[2][s4 + 2]) * inv;
            o.w = (acc[3] + w0 * sLnV[0][s4 + 3] + w1 * sLnV[1][s4 + 3] + w2 * sLnV[2][s4 + 3]) * inv;
            *(float4*)&outp[((size_t)(b * LQ + q0 + q)) * DM + h * DHD + s4] = o;
        }
    }
}

// ---------------------------------------------------------------------------
extern "C" void kernel_launch(void* const* d_in, const int* in_sizes, int n_in,
                              void* d_out, int out_size, void* d_ws, size_t ws_size,
                              hipStream_t stream) {
    const float* hidden  = (const float*)d_in[0];
    const float* context = (const float*)d_in[1];
    const float* mask    = (const float*)d_in[2];
    const int*   garc    = (const int*)d_in[3];
    const float* Wq = (const float*)d_in[4];
    const float* bq = (const float*)d_in[5];
    const float* Wk = (const float*)d_in[6];
    const float* bk = (const float*)d_in[7];
    const float* Wv = (const float*)d_in[8];
    const float* bv = (const float*)d_in[9];
    const float* dpk  = (const float*)d_in[10];
    const float* dpv  = (const float*)d_in[11];
    const float* lnkg = (const float*)d_in[12];
    const float* lnkb = (const float*)d_in[13];
    const float* lnvg = (const float*)d_in[14];
    const float* lnvb = (const float*)d_in[15];
    float* out = (float*)d_out;

    float* ws = (float*)d_ws;
    const size_t perT = (size_t)NB * NH * LQ * DHD;   // 1,572,864
    float* Qw  = ws;
    float* Kw  = ws + perT;
    float* Vw  = ws + 2 * perT;
    float* lnK = ws + 3 * perT;
    float* lnV = lnK + 192;

    prep_ln_kernel<<<1, 64, 0, stream>>>(dpk, dpv, lnkg, lnkb, lnvg, lnvb, lnK, lnV);
    qkv_kernel<<<dim3(32, 36), 256, 0, stream>>>(hidden, context,
                                                 Wq, bq, Wk, bk, Wv, bv,
                                                 Qw, Kw, Vw);
    attn_kernel<<<1536, 256, 0, stream>>>(Qw, Kw, Vw, mask, garc, lnK, lnV, out);
}

// Round 2
// 163.721 us; speedup vs baseline: 2.0260x; 2.0260x over previous
//
#include <hip/hip_runtime.h>
#include <hip/hip_fp16.h>

#define NB 4
#define NH 12
#define DHD 64
#define LQ 512
#define LK 512
#define DM 768

typedef __attribute__((ext_vector_type(4))) _Float16 f16x4;
typedef __attribute__((ext_vector_type(8))) _Float16 f16x8;
typedef __attribute__((ext_vector_type(4))) float f32x4;

// ---------------------------------------------------------------------------
// Kernel 0: LayerNorm of the 3x64 relation embedding tables (fp32 out).
// ---------------------------------------------------------------------------
__global__ __launch_bounds__(64) void prep_ln_kernel(
    const float* __restrict__ dpk, const float* __restrict__ dpv,
    const float* __restrict__ gk, const float* __restrict__ bk,
    const float* __restrict__ gv, const float* __restrict__ bv,
    float* __restrict__ lnK, float* __restrict__ lnV)
{
    int lane = threadIdx.x;
    for (int r = 0; r < 3; ++r) {
        {
            float x = dpk[r * DHD + lane];
            float s = x;
            #pragma unroll
            for (int o = 1; o < 64; o <<= 1) s += __shfl_xor(s, o);
            float mu = s * (1.0f / 64.0f);
            float d = x - mu;
            float v = d * d;
            #pragma unroll
            for (int o = 1; o < 64; o <<= 1) v += __shfl_xor(v, o);
            lnK[r * DHD + lane] = d * rsqrtf(v * (1.0f / 64.0f) + 1e-5f) * gk[lane] + bk[lane];
        }
        {
            float x = dpv[r * DHD + lane];
            float s = x;
            #pragma unroll
            for (int o = 1; o < 64; o <<= 1) s += __shfl_xor(s, o);
            float mu = s * (1.0f / 64.0f);
            float d = x - mu;
            float v = d * d;
            #pragma unroll
            for (int o = 1; o < 64; o <<= 1) v += __shfl_xor(v, o);
            lnV[r * DHD + lane] = d * rsqrtf(v * (1.0f / 64.0f) + 1e-5f) * gv[lane] + bv[lane];
        }
    }
}

// ---------------------------------------------------------------------------
// Kernel 1: fused QKV projection with fp16 MFMA.
// Tile: 128 (M) x 64 (N=one head), K-step 32, 24 iters. 256 threads = 4 waves
// in 2x2; each wave does 4x2 MFMA tiles of 16x16x32.
// Q,K written [B,H,L,64] f16; V written transposed [B,H,64,L] f16.
// fp32->f16 conversion happens during LDS staging (no separate pass).
// Strides 40/72/136 halves keep ds_read_b128 16B-aligned, <=2-way banks.
// ---------------------------------------------------------------------------
__global__ __launch_bounds__(256) void qkv_mfma(
    const float* __restrict__ hidden, const float* __restrict__ context,
    const float* __restrict__ Wq, const float* __restrict__ bq,
    const float* __restrict__ Wk, const float* __restrict__ bk,
    const float* __restrict__ Wv, const float* __restrict__ bv,
    _Float16* __restrict__ Qh, _Float16* __restrict__ Kh,
    _Float16* __restrict__ VTh)
{
    __shared__ __align__(16) char smem[18432];
    _Float16 (*sA)[40]   = (_Float16(*)[40])smem;            // 128x40 = 10240 B
    _Float16 (*sBT)[40]  = (_Float16(*)[40])(smem + 10240);  // 64x40  =  5120 B
    _Float16 (*sC)[72]   = (_Float16(*)[72])smem;            // 128x72 = 18432 B
    _Float16 (*sVT)[136] = (_Float16(*)[136])smem;           // 64x136 = 17408 B

    const int t = threadIdx.x;
    const int w = t >> 6, lane = t & 63, g = lane >> 4, c16 = lane & 15;
    const int wm = w >> 1, wn = w & 1;
    const int mat = blockIdx.y / NH, head = blockIdx.y % NH;
    const float* X    = (mat == 0) ? hidden : context;
    const float* W    = (mat == 0) ? Wq : (mat == 1) ? Wk : Wv;
    const float* bias = (mat == 0) ? bq : (mat == 1) ? bk : bv;
    const int m0 = blockIdx.x * 128, n0 = head * DHD;

    f32x4 acc[4][2];
    #pragma unroll
    for (int mt = 0; mt < 4; ++mt)
        #pragma unroll
        for (int nt = 0; nt < 2; ++nt) acc[mt][nt] = (f32x4){0.f, 0.f, 0.f, 0.f};

    for (int kt = 0; kt < 24; ++kt) {
        __syncthreads();
        // stage A tile 128x32 (fp32 -> f16)
        #pragma unroll
        for (int p = 0; p < 4; ++p) {
            int idx = t + p * 256;
            int row = idx >> 3, c4 = idx & 7;
            float4 xv = *(const float4*)&X[(size_t)(m0 + row) * DM + kt * 32 + c4 * 4];
            f16x4 hv = { (_Float16)xv.x, (_Float16)xv.y, (_Float16)xv.z, (_Float16)xv.w };
            *(f16x4*)&sA[row][c4 * 4] = hv;
        }
        // stage B tile 32x64 transposed -> sBT[n][k]
        #pragma unroll
        for (int p = 0; p < 2; ++p) {
            int idx = t + p * 256;
            int kk = idx >> 4, c4 = idx & 15;
            float4 wv = *(const float4*)&W[(size_t)(kt * 32 + kk) * DM + n0 + c4 * 4];
            sBT[c4 * 4 + 0][kk] = (_Float16)wv.x;
            sBT[c4 * 4 + 1][kk] = (_Float16)wv.y;
            sBT[c4 * 4 + 2][kk] = (_Float16)wv.z;
            sBT[c4 * 4 + 3][kk] = (_Float16)wv.w;
        }
        __syncthreads();
        f16x8 af[4], bf[2];
        #pragma unroll
        for (int mt = 0; mt < 4; ++mt)
            af[mt] = *(const f16x8*)&sA[wm * 64 + mt * 16 + c16][8 * g];
        #pragma unroll
        for (int nt = 0; nt < 2; ++nt)
            bf[nt] = *(const f16x8*)&sBT[wn * 32 + nt * 16 + c16][8 * g];
        #pragma unroll
        for (int mt = 0; mt < 4; ++mt)
            #pragma unroll
            for (int nt = 0; nt < 2; ++nt)
                acc[mt][nt] = __builtin_amdgcn_mfma_f32_16x16x32_f16(
                    af[mt], bf[nt], acc[mt][nt], 0, 0, 0);
    }

    __syncthreads();
    float bb0 = bias[n0 + wn * 32 + c16];
    float bb1 = bias[n0 + wn * 32 + 16 + c16];
    if (mat < 2) {
        // C frags -> LDS [m][n], then coalesced 16B row stores
        #pragma unroll
        for (int mt = 0; mt < 4; ++mt)
            #pragma unroll
            for (int nt = 0; nt < 2; ++nt) {
                float bbn = nt ? bb1 : bb0;
                #pragma unroll
                for (int r = 0; r < 4; ++r) {
                    int m = wm * 64 + mt * 16 + 4 * g + r;
                    int n = wn * 32 + nt * 16 + c16;
                    sC[m][n] = (_Float16)(acc[mt][nt][r] + bbn);
                }
            }
        __syncthreads();
        _Float16* dst = (mat == 0) ? Qh : Kh;
        #pragma unroll
        for (int p = 0; p < 4; ++p) {
            int idx = t + p * 256;
            int row = idx >> 3, c8 = idx & 7;
            int m = m0 + row, bbat = m >> 9, l = m & 511;
            *(f16x8*)&dst[((size_t)(bbat * NH + head) * LQ + l) * DHD + c8 * 8] =
                *(const f16x8*)&sC[row][c8 * 8];
        }
    } else {
        // V: C frags -> LDS transposed [n][m], then coalesced 16B row stores
        #pragma unroll
        for (int mt = 0; mt < 4; ++mt)
            #pragma unroll
            for (int nt = 0; nt < 2; ++nt) {
                float bbn = nt ? bb1 : bb0;
                #pragma unroll
                for (int r = 0; r < 4; ++r) {
                    int m = wm * 64 + mt * 16 + 4 * g + r;
                    int n = wn * 32 + nt * 16 + c16;
                    sVT[n][m] = (_Float16)(acc[mt][nt][r] + bbn);
                }
            }
        __syncthreads();
        int bbat = m0 >> 9, l0 = m0 & 511;
        #pragma unroll
        for (int p = 0; p < 4; ++p) {
            int idx = t + p * 256;
            int n = idx >> 4, c8 = idx & 15;
            *(f16x8*)&VTh[((size_t)(bbat * NH + head) * DHD + n) * LK + l0 + c8 * 8] =
                *(const f16x8*)&sVT[n][c8 * 8];
        }
    }
}

// ---------------------------------------------------------------------------
// Kernel 2: attention with fp16 MFMA. Block = (b, h, 16-query tile), 256 thr
// = 4 waves; wave w owns keys [w*128, w*128+128) for QK^T/softmax and
// d-cols [w*16, w*16+16) for PV. Scores stay in C-fragments (registers);
// only exp'd P hits LDS (f16, 16x520). Arc codes staged once as u8 and
// packed into registers for the exp pass.
// ---------------------------------------------------------------------------
__global__ __launch_bounds__(256) void attn_mfma(
    const _Float16* __restrict__ Qh, const _Float16* __restrict__ Kh,
    const _Float16* __restrict__ VTh, const float* __restrict__ maskp,
    const int* __restrict__ garc, const float* __restrict__ lnK,
    const float* __restrict__ lnV, float* __restrict__ outp)
{
    __shared__ __align__(16) _Float16 sP[16][520];   // 16640 B, stride 1040B=16*65
    __shared__ unsigned char sArc[16][512];          // 8192 B
    __shared__ float sTb[16][4];
    __shared__ float sMax[4][16];
    __shared__ float sStat[4][16][4];
    __shared__ float sFin[16][4];

    const int t = threadIdx.x;
    const int w = t >> 6, lane = t & 63, g = lane >> 4, c16 = lane & 15;
    const int bx = blockIdx.x;
    const int qt = bx & 31, h = (bx >> 5) % NH, b = bx / (32 * NH);
    const int q0 = qt * 16;
    const int kw = w * 128;

    const _Float16* Qb = Qh + ((size_t)(b * NH + h) * LQ) * DHD;
    const _Float16* Kb = Kh + ((size_t)(b * NH + h) * LK) * DHD;
    const _Float16* Vb = VTh + ((size_t)(b * NH + h) * DHD) * LK;

    // stage arc rows (16 x 512 int32 -> u8)
    const int* garcRow = garc + ((size_t)(b * LQ + q0)) * LK;
    unsigned char* sArcFlat = &sArc[0][0];
    #pragma unroll
    for (int p = 0; p < 8; ++p) {
        int idx = t + p * 256;
        int4 a4 = *(const int4*)&garcRow[idx * 4];
        uchar4 u = { (unsigned char)a4.x, (unsigned char)a4.y,
                     (unsigned char)a4.z, (unsigned char)a4.w };
        *(uchar4*)&sArcFlat[idx * 4] = u;
    }
    // tb[q][r] = q . lnK[r]  (192 threads, 4-lane partial sums)
    if (t < 192) {
        int q = t / 12, rem = t % 12, rr = rem >> 2, part = rem & 3;
        float a = 0.f;
        const _Float16* qrow = Qb + (q0 + q) * DHD;
        #pragma unroll
        for (int d0 = 0; d0 < 16; ++d0) {
            int d = part * 16 + d0;
            a += (float)qrow[d] * lnK[rr * 64 + d];
        }
        a += __shfl_xor(a, 1);
        a += __shfl_xor(a, 2);
        if (part == 0) sTb[q][rr] = a;
    }
    // Q A-fragments straight from global (16B per lane)
    f16x8 qa0 = *(const f16x8*)&Qb[(q0 + c16) * DHD + 8 * g];
    f16x8 qa1 = *(const f16x8*)&Qb[(q0 + c16) * DHD + 32 + 8 * g];
    __syncthreads();

    // QK^T + score fixup (scale, arc term, mask); scores stay in regs
    f32x4 c[8];
    int aPack[8];
    float rm[4] = {-1e30f, -1e30f, -1e30f, -1e30f};
    #pragma unroll
    for (int tt = 0; tt < 8; ++tt) {
        int kg = kw + tt * 16 + c16;
        f16x8 kb0 = *(const f16x8*)&Kb[kg * DHD + 8 * g];
        f16x8 kb1 = *(const f16x8*)&Kb[kg * DHD + 32 + 8 * g];
        f32x4 s = (f32x4){0.f, 0.f, 0.f, 0.f};
        s = __builtin_amdgcn_mfma_f32_16x16x32_f16(qa0, kb0, s, 0, 0, 0);
        s = __builtin_amdgcn_mfma_f32_16x16x32_f16(qa1, kb1, s, 0, 0, 0);
        float mv = maskp[b * LK + kg];
        int ap = 0;
        #pragma unroll
        for (int r = 0; r < 4; ++r) {
            int a = sArc[4 * g + r][kg];
            ap |= a << (8 * r);
            float sv = s[r] * 0.125f + sTb[4 * g + r][a] + mv;
            s[r] = sv;
            rm[r] = fmaxf(rm[r], sv);
        }
        c[tt] = s;
        aPack[tt] = ap;
    }

    // row max: shuffle over the 16 key-lanes, then cross-wave via LDS
    #pragma unroll
    for (int r = 0; r < 4; ++r) {
        float m = rm[r];
        m = fmaxf(m, __shfl_xor(m, 1));
        m = fmaxf(m, __shfl_xor(m, 2));
        m = fmaxf(m, __shfl_xor(m, 4));
        m = fmaxf(m, __shfl_xor(m, 8));
        rm[r] = m;
    }
    if (c16 == 0) {
        #pragma unroll
        for (int r = 0; r < 4; ++r) sMax[w][4 * g + r] = rm[r];
    }
    __syncthreads();
    float Mr[4];
    #pragma unroll
    for (int r = 0; r < 4; ++r) {
        int q = 4 * g + r;
        Mr[r] = fmaxf(fmaxf(sMax[0][q], sMax[1][q]), fmaxf(sMax[2][q], sMax[3][q]));
    }

    // exp, row sums + 3 arc-bucket sums (unnormalized), P -> LDS f16
    float rs[4] = {0, 0, 0, 0}, b0s[4] = {0, 0, 0, 0},
          b1s[4] = {0, 0, 0, 0}, b2s[4] = {0, 0, 0, 0};
    #pragma unroll
    for (int tt = 0; tt < 8; ++tt) {
        int kg = kw + tt * 16 + c16;
        #pragma unroll
        for (int r = 0; r < 4; ++r) {
            float e = __expf(c[tt][r] - Mr[r]);
            int a = (aPack[tt] >> (8 * r)) & 255;
            rs[r] += e;
            b0s[r] += (a == 0) ? e : 0.f;
            b1s[r] += (a == 1) ? e : 0.f;
            b2s[r] += (a == 2) ? e : 0.f;
            sP[4 * g + r][kg] = (_Float16)e;
        }
    }
    #pragma unroll
    for (int r = 0; r < 4; ++r) {
        #pragma unroll
        for (int o = 1; o < 16; o <<= 1) {
            rs[r]  += __shfl_xor(rs[r], o);
            b0s[r] += __shfl_xor(b0s[r], o);
            b1s[r] += __shfl_xor(b1s[r], o);
            b2s[r] += __shfl_xor(b2s[r], o);
        }
    }
    if (c16 == 0) {
        #pragma unroll
        for (int r = 0; r < 4; ++r) {
            float4 v = make_float4(rs[r], b0s[r], b1s[r], b2s[r]);
            *(float4*)&sStat[w][4 * g + r][0] = v;
        }
    }
    __syncthreads();   // sP + sStat visible to all waves
    if (t < 16) {
        float4 tot = make_float4(0.f, 0.f, 0.f, 0.f);
        #pragma unroll
        for (int ww = 0; ww < 4; ++ww) {
            float4 v = *(const float4*)&sStat[ww][t][0];
            tot.x += v.x; tot.y += v.y; tot.z += v.z; tot.w += v.w;
        }
        sFin[t][0] = 1.0f / tot.x;
        sFin[t][1] = tot.y; sFin[t][2] = tot.z; sFin[t][3] = tot.w;
    }

    // PV: A from sP (LDS), B from transposed V (global, contiguous 16B)
    f32x4 o = (f32x4){0.f, 0.f, 0.f, 0.f};
    const _Float16* vrow = Vb + (size_t)(w * 16 + c16) * LK;
    #pragma unroll
    for (int ktile = 0; ktile < 16; ++ktile) {
        f16x8 pa = *(const f16x8*)&sP[c16][ktile * 32 + 8 * g];
        f16x8 vb = *(const f16x8*)&vrow[ktile * 32 + 8 * g];
        o = __builtin_amdgcn_mfma_f32_16x16x32_f16(pa, vb, o, 0, 0, 0);
    }
    __syncthreads();   // sFin visible

    // epilogue: rank-3 lnV correction + normalize, store fp32
    int d = w * 16 + c16;
    float lv0 = lnV[d], lv1 = lnV[64 + d], lv2 = lnV[128 + d];
    #pragma unroll
    for (int r = 0; r < 4; ++r) {
        int q = 4 * g + r;
        float4 st = *(const float4*)&sFin[q][0];
        float val = (o[r] + st.y * lv0 + st.z * lv1 + st.w * lv2) * st.x;
        outp[((size_t)(b * LQ + q0 + q)) * DM + h * DHD + d] = val;
    }
}

// ---------------------------------------------------------------------------
extern "C" void kernel_launch(void* const* d_in, const int* in_sizes, int n_in,
                              void* d_out, int out_size, void* d_ws, size_t ws_size,
                              hipStream_t stream) {
    const float* hidden  = (const float*)d_in[0];
    const float* context = (const float*)d_in[1];
    const float* mask    = (const float*)d_in[2];
    const int*   garc    = (const int*)d_in[3];
    const float* Wq = (const float*)d_in[4];
    const float* bq = (const float*)d_in[5];
    const float* Wk = (const float*)d_in[6];
    const float* bk = (const float*)d_in[7];
    const float* Wv = (const float*)d_in[8];
    const float* bv = (const float*)d_in[9];
    const float* dpk  = (const float*)d_in[10];
    const float* dpv  = (const float*)d_in[11];
    const float* lnkg = (const float*)d_in[12];
    const float* lnkb = (const float*)d_in[13];
    const float* lnvg = (const float*)d_in[14];
    const float* lnvb = (const float*)d_in[15];
    float* out = (float*)d_out;

    const size_t perT = (size_t)NB * NH * LQ * DHD;   // 1,572,864 halves
    _Float16* Qh  = (_Float16*)d_ws;
    _Float16* Kh  = Qh + perT;
    _Float16* VTh = Kh + perT;
    float* lnK = (float*)(VTh + perT);                // byte offset 9,437,184
    float* lnV = lnK + 192;

    prep_ln_kernel<<<1, 64, 0, stream>>>(dpk, dpv, lnkg, lnkb, lnvg, lnvb, lnK, lnV);
    qkv_mfma<<<dim3(16, 36), 256, 0, stream>>>(hidden, context,
                                               Wq, bq, Wk, bk, Wv, bv,
                                               Qh, Kh, VTh);
    attn_mfma<<<1536, 256, 0, stream>>>(Qh, Kh, VTh, mask, garc, lnK, lnV, out);
}